// Round 6
// baseline (479.467 us; speedup 1.0000x reference)
//
#include <hip/hip_runtime.h>
#include <hip/hip_bf16.h>

#define NN 8192
#define MM 128
#define EPSF 1e-4f
#define SHIFT 30.0f

typedef __bf16 bf16x8 __attribute__((ext_vector_type(8)));
typedef __bf16 bf16x4 __attribute__((ext_vector_type(4)));
typedef float floatx4 __attribute__((ext_vector_type(4)));

// fp32 -> bf16 conversion of out1 & out2 (blockIdx.y selects tensor)
__global__ void convert_kernel(const float* __restrict__ in0,
                               const float* __restrict__ in1,
                               __bf16* __restrict__ o0,
                               __bf16* __restrict__ o1) {
    const float* in = blockIdx.y ? in1 : in0;
    __bf16* out = blockIdx.y ? o1 : o0;
    int i = (blockIdx.x * blockDim.x + threadIdx.x) * 4;
    float4 v = *reinterpret_cast<const float4*>(in + i);
    bf16x4 o = { (__bf16)v.x, (__bf16)v.y, (__bf16)v.z, (__bf16)v.w };
    *reinterpret_cast<bf16x4*>(out + i) = o;
}

#define LOAD_A(dst, ptr)                                                   \
    do {                                                                   \
        dst[0] = *reinterpret_cast<const bf16x8*>((ptr) + 0);              \
        dst[1] = *reinterpret_cast<const bf16x8*>((ptr) + 32);             \
        dst[2] = *reinterpret_cast<const bf16x8*>((ptr) + 64);             \
        dst[3] = *reinterpret_cast<const bf16x8*>((ptr) + 96);             \
    } while (0)

// ONE pass over S = A @ B^T producing BOTH row sums (sums[0:NN]) and col
// sums (sums[NN:2NN]) of exp(S-SHIFT). 16 half-steps of 32 cols with a
// rolling 2-buffer register prefetch of B (loads always one half in flight).
__global__ __launch_bounds__(256)
void sums_kernel(const __bf16* __restrict__ A, const __bf16* __restrict__ B,
                 float* __restrict__ sums) {
    const int tid = threadIdx.x;
    const int w = tid >> 6, lane = tid & 63, q = lane >> 4, ln = lane & 15;
    const int i0 = blockIdx.y * 128 + w * 32;   // 32 rows per wave (2 row-groups)
    const int jbase = blockIdx.x * 512;         // 512 cols per block

    const floatx4 accInit = {-SHIFT, -SHIFT, -SHIFT, -SHIFT};

    bf16x8 a[2][4];
    #pragma unroll
    for (int rg = 0; rg < 2; ++rg)
        LOAD_A(a[rg], A + (size_t)(i0 + rg * 16 + ln) * MM + q * 8);

    float p[2][4] = {{0.f, 0.f, 0.f, 0.f}, {0.f, 0.f, 0.f, 0.f}};

    bf16x8 b[2][2][4];  // [buf][cg-within-half][k]
    #define LOAD_HALF(buf, h)                                                  \
        do {                                                                   \
            const int j0_ = jbase + (h) * 32;                                  \
            LOAD_A(b[buf][0], B + (size_t)(j0_ + ln) * MM + q * 8);            \
            LOAD_A(b[buf][1], B + (size_t)(j0_ + 16 + ln) * MM + q * 8);       \
        } while (0)

    LOAD_HALF(0, 0);
    #pragma unroll
    for (int h = 0; h < 16; ++h) {
        const int buf = h & 1;
        if (h < 15) LOAD_HALF(buf ^ 1, h + 1);
        #pragma unroll
        for (int c = 0; c < 2; ++c) {
            floatx4 acc0 = accInit, acc1 = accInit;
            #pragma unroll
            for (int k = 0; k < 4; ++k) {
                acc0 = __builtin_amdgcn_mfma_f32_16x16x32_bf16(a[0][k], b[buf][c][k], acc0, 0, 0, 0);
                acc1 = __builtin_amdgcn_mfma_f32_16x16x32_bf16(a[1][k], b[buf][c][k], acc1, 0, 0, 0);
            }
            float e0[4], e1[4];
            #pragma unroll
            for (int r = 0; r < 4; ++r) {
                e0[r] = __expf(acc0[r]);
                e1[r] = __expf(acc1[r]);
                p[0][r] += e0[r];
                p[1][r] += e1[r];
            }
            float cs = ((e0[0] + e0[1]) + (e0[2] + e0[3])) +
                       ((e1[0] + e1[1]) + (e1[2] + e1[3]));
            cs += __shfl_xor(cs, 16);
            cs += __shfl_xor(cs, 32);
            if (q == 0) atomicAdd(&sums[NN + jbase + h * 32 + c * 16 + ln], cs);
        }
    }

    #pragma unroll
    for (int m = 1; m <= 8; m <<= 1)
        #pragma unroll
        for (int rg = 0; rg < 2; ++rg)
            #pragma unroll
            for (int r = 0; r < 4; ++r)
                p[rg][r] += __shfl_xor(p[rg][r], m);
    if (ln == 0)
        #pragma unroll
        for (int rg = 0; rg < 2; ++rg)
            #pragma unroll
            for (int r = 0; r < 4; ++r)
                atomicAdd(&sums[i0 + rg * 16 + q * 4 + r], p[rg][r]);
}

__global__ void recip_kernel(const float* __restrict__ s, float* __restrict__ r) {
    int i = blockIdx.x * 256 + threadIdx.x;
    r[i] = 1.0f / s[i];
}

// loss = sum_ij -label[i,j] * log( (e*rl_i+eps)*(e*rc_j+eps) ),  e = exp(s-SHIFT)
// TRANSPOSED MFMA: acc = mfma(b, a) gives lane = one S-row, 4 consecutive
// S-cols per acc reg. label float4s are double-buffered in registers:
// js+1's 8 nontemporal loads are issued before computing js (the label
// stream is the HBM-latency term; prefetch gives it a full js of overlap).
__global__ __launch_bounds__(256)
void loss_kernel(const __bf16* __restrict__ A, const __bf16* __restrict__ B,
                 const float* __restrict__ lrowR, const float* __restrict__ lcolR,
                 const float* __restrict__ label, float* __restrict__ out) {
    const int tid = threadIdx.x;
    const int w = tid >> 6, lane = tid & 63, q = lane >> 4, ln = lane & 15;
    const int i0 = blockIdx.y * 128 + w * 32;   // 32 rows per wave
    const int jbase = blockIdx.x * 256;         // 256 cols per block

    const floatx4 accInit = {-SHIFT, -SHIFT, -SHIFT, -SHIFT};

    bf16x8 a[2][4];
    float rl[2];
    const float* labp[2];
    #pragma unroll
    for (int rg = 0; rg < 2; ++rg) {
        const int row = i0 + rg * 16 + ln;
        LOAD_A(a[rg], A + (size_t)row * MM + q * 8);
        rl[rg] = lrowR[row];
        labp[rg] = label + (size_t)row * NN;
    }

    floatx4 lb[2][2][4];  // [buf][rg][cg]
    #define LOAD_LB(buf, js)                                                    \
        do {                                                                    \
            const int jb_ = jbase + (js) * 64 + q * 4;                          \
            _Pragma("unroll")                                                   \
            for (int cg_ = 0; cg_ < 4; ++cg_) {                                 \
                lb[buf][0][cg_] = __builtin_nontemporal_load(                   \
                    reinterpret_cast<const floatx4*>(&labp[0][jb_ + cg_ * 16]));\
                lb[buf][1][cg_] = __builtin_nontemporal_load(                   \
                    reinterpret_cast<const floatx4*>(&labp[1][jb_ + cg_ * 16]));\
            }                                                                   \
        } while (0)

    LOAD_LB(0, 0);
    float lacc[4] = {0.f, 0.f, 0.f, 0.f};

    #pragma unroll
    for (int js = 0; js < 4; ++js) {
        const int buf = js & 1;
        if (js < 3) LOAD_LB(buf ^ 1, js + 1);
        const int j0 = jbase + js * 64;
        floatx4 rc[4];
        #pragma unroll
        for (int cg = 0; cg < 4; ++cg)
            rc[cg] = *reinterpret_cast<const floatx4*>(&lcolR[j0 + cg * 16 + q * 4]);
        #pragma unroll
        for (int cg = 0; cg < 4; ++cg) {
            const __bf16* br = B + (size_t)(j0 + cg * 16 + ln) * MM + q * 8;
            bf16x8 b[4];
            LOAD_A(b, br);
            floatx4 acc0 = accInit, acc1 = accInit;
            #pragma unroll
            for (int k = 0; k < 4; ++k) {
                acc0 = __builtin_amdgcn_mfma_f32_16x16x32_bf16(b[k], a[0][k], acc0, 0, 0, 0);
                acc1 = __builtin_amdgcn_mfma_f32_16x16x32_bf16(b[k], a[1][k], acc1, 0, 0, 0);
            }
            #pragma unroll
            for (int r = 0; r < 4; ++r) {
                float e0 = __expf(acc0[r]);
                float t0 = __logf(fmaf(e0, rl[0], EPSF) * fmaf(e0, rc[cg][r], EPSF));
                lacc[r] = fmaf(lb[buf][0][cg][r], t0, lacc[r]);
                float e1 = __expf(acc1[r]);
                float t1 = __logf(fmaf(e1, rl[1], EPSF) * fmaf(e1, rc[cg][r], EPSF));
                lacc[r] = fmaf(lb[buf][1][cg][r], t1, lacc[r]);
            }
        }
    }

    float lsum = (lacc[0] + lacc[1]) + (lacc[2] + lacc[3]);
    #pragma unroll
    for (int m = 1; m <= 32; m <<= 1) lsum += __shfl_xor(lsum, m);
    __shared__ float red[4];
    if (lane == 0) red[w] = lsum;
    __syncthreads();
    if (tid == 0) atomicAdd(out, -((red[0] + red[1]) + (red[2] + red[3])));
}

extern "C" void kernel_launch(void* const* d_in, const int* in_sizes, int n_in,
                              void* d_out, int out_size, void* d_ws, size_t ws_size,
                              hipStream_t stream) {
    const float* out1 = (const float*)d_in[0];
    const float* out2 = (const float*)d_in[1];
    const float* label = (const float*)d_in[2];

    char* ws = (char*)d_ws;
    __bf16* out1b = (__bf16*)ws;                          // 2 MB
    __bf16* out2b = (__bf16*)(ws + (size_t)(2 << 20));    // 2 MB
    float* sums   = (float*)(ws + (size_t)(4 << 20));     // 2*NN floats (64 KB)
    float* recips = sums + 2 * NN;                        // 2*NN floats (64 KB)

    hipMemsetAsync(sums, 0, 2 * NN * sizeof(float), stream);
    hipMemsetAsync(d_out, 0, sizeof(float), stream);

    convert_kernel<<<dim3(1024, 2), 256, 0, stream>>>(out1, out2, out1b, out2b);

    // single S pass -> both row sums (sums[0:NN]) and col sums (sums[NN:2NN])
    sums_kernel<<<dim3(16, 64), 256, 0, stream>>>(out2b, out1b, sums);
    recip_kernel<<<dim3(64), 256, 0, stream>>>(sums, recips);

    loss_kernel<<<dim3(32, 64), 256, 0, stream>>>(out2b, out1b,
                                                  recips,          // 1/rowsum
                                                  recips + NN,     // 1/colsum
                                                  label, (float*)d_out);
}